// Round 4
// baseline (28270.752 us; speedup 1.0000x reference)
//
#include <hip/hip_runtime.h>
#include <stdint.h>

// R8: TreeRNN T=256, D=512 (batch!), H=E=256, V=8192.
// STRUCTURAL RESET after two failed same-XCD-L2 exchange protocols (R6/R7):
// rows are independent (D is batch), so partition by ROWS ONLY:
//   32 blocks x 1024 threads; block owns 16 rows x all 256 cols x both GRUs.
//   => h[row][:] is block-local. ZERO cross-block communication. No flags,
//   no polls, no workspace, no XCD/coherence assumptions. Robust by design.
// Weights stream from global per step (B-fragments); all blocks read the same
// 1.57 MB/step -> permanently L2-resident per XCD. fp32 state carry lives in
// REGISTERS (each thread computes both GRUs for its (row,col) and selects by
// edge locally). Gate math bit-matches the proven R4 kernel: r,z gates merge
// x/h chains (bias pre-sum, pure reorder); n-gate keeps separate x-side and
// h-side accumulators for in + r*hn.

#define TT   256
#define DDIM 512
#define LSTR 264   // LDS row stride in bf16 elems (256 + 8 pad)

typedef float    float4v __attribute__((ext_vector_type(4)));
typedef short    short8  __attribute__((ext_vector_type(8)));

__device__ __forceinline__ unsigned short f2bf(float f){
  uint32_t u = __float_as_uint(f);
  u += 0x7fffu + ((u >> 16) & 1u);          // RNE, finite inputs
  return (unsigned short)(u >> 16);
}
__device__ __forceinline__ float bf2f(unsigned short h){
  return __uint_as_float(((uint32_t)h) << 16);
}
__device__ __forceinline__ float4v splat4(float v){ return (float4v){v, v, v, v}; }

__global__ __launch_bounds__(1024, 1)
void treernn_main(const int* __restrict__ nodes,
                  const unsigned char* __restrict__ edges,
                  const unsigned char* __restrict__ hinit,
                  const unsigned char* __restrict__ emb,
                  const unsigned char* __restrict__ cWih, const unsigned char* __restrict__ cWhh,
                  const unsigned char* __restrict__ cbih, const unsigned char* __restrict__ cbhh,
                  const unsigned char* __restrict__ sWih, const unsigned char* __restrict__ sWhh,
                  const unsigned char* __restrict__ sbih, const unsigned char* __restrict__ sbhh,
                  unsigned char* __restrict__ out)
{
  __shared__ __align__(16) unsigned short xstg[2][16 * LSTR];  // x_t bf16, dbuf
  __shared__ __align__(16) unsigned short hstg[2][16 * LSTR];  // h_t bf16, dbuf
  __shared__ int det[8];

  const int tid  = threadIdx.x;
  const int lane = tid & 63;
  const int wv   = tid >> 6;        // wave 0..15: owns cols [wv*16, +16)
  const int quad = lane >> 4;
  const int l16  = lane & 15;
  const int d0   = blockIdx.x * 16; // rows [d0, d0+16)
  const int col  = wv * 16 + l16;   // this thread's h-column (C/D col = lane&15)

  // ---------------- runtime dtype detection (proven discriminators) ----------------
  if (tid < 8) det[tid] = 0;
  __syncthreads();
  {
    const unsigned short* hu = (const unsigned short*)hinit;
    int ce = 0;
    for (int i = tid; i < 4096; i += 1024){
      const int e = (hu[i] >> 7) & 0xFF;
      ce += (e >= 100 && e <= 130) ? 1 : 0;
    }
    atomicAdd(&det[0], ce);
    const uint32_t* ewp = (const uint32_t*)edges;
    int b01 = 0, w01 = 0, wf = 0, hb = 0;
    for (int i = tid; i < 512; i += 1024){
      const uint32_t w = ewp[i];
      w01 += (w <= 1u) ? 1 : 0;
      wf  += (w == 0u || w == 0x3F800000u) ? 1 : 0;
      const uint32_t h0 = w & 0xFFFFu, h1 = w >> 16;
      hb  += ((h0 == 0u || h0 == 0x3F80u) ? 1 : 0) + ((h1 == 0u || h1 == 0x3F80u) ? 1 : 0);
      b01 += (((w      ) & 0xFFu) <= 1u ? 1 : 0) + (((w >> 8 ) & 0xFFu) <= 1u ? 1 : 0)
           + (((w >> 16) & 0xFFu) <= 1u ? 1 : 0) + (((w >> 24)        ) <= 1u ? 1 : 0);
    }
    atomicAdd(&det[1], b01); atomicAdd(&det[2], w01);
    atomicAdd(&det[3], wf);  atomicAdd(&det[4], hb);
  }
  __syncthreads();
  const int fdt = (det[0] >= 3480) ? 1 : 0;   // 1 = floats are bf16
  int efmt;                                    // 0=u8, 1=i32, 2=f32, 3=bf16
  if      (det[2] == 512)  efmt = 1;
  else if (det[1] == 2048) efmt = 0;
  else if (det[4] == 1024) efmt = 3;
  else if (det[3] == 512)  efmt = 2;
  else                     efmt = 0;

  // ---------------- per-thread constants ----------------
  const unsigned char* WihP[2] = {cWih, sWih};   // g=0 child, g=1 sibling
  const unsigned char* WhhP[2] = {cWhh, sWhh};
  const unsigned char* bihP[2] = {cbih, sbih};
  const unsigned char* bhhP[2] = {cbhh, sbhh};

  // biases: r,z merged (bi+bh); n kept split (n = tanh(in + r*hn))
  float bRZ[2][2], bNI[2], bNH[2];
  #pragma unroll
  for (int g = 0; g < 2; ++g){
    #pragma unroll
    for (int ga = 0; ga < 2; ++ga){
      const int o = ga * 256 + col;
      const float bi = fdt ? bf2f(((const unsigned short*)bihP[g])[o]) : ((const float*)bihP[g])[o];
      const float bh = fdt ? bf2f(((const unsigned short*)bhhP[g])[o]) : ((const float*)bhhP[g])[o];
      bRZ[g][ga] = bi + bh;
    }
    const int o2 = 512 + col;
    bNI[g] = fdt ? bf2f(((const unsigned short*)bihP[g])[o2]) : ((const float*)bihP[g])[o2];
    bNH[g] = fdt ? bf2f(((const unsigned short*)bhhP[g])[o2]) : ((const float*)bhhP[g])[o2];
  }

  // B-fragment element offset within a weight matrix: row (ga*256+col), k (kc*32+quad*8)
  const size_t coff = (size_t)col * 256 + (size_t)quad * 8;

  // fp32 state carry in registers: rows quad*4+0..3 at this thread's col
  float hold[4];
  #pragma unroll
  for (int r = 0; r < 4; ++r){
    const size_t idx = (size_t)(d0 + quad * 4 + r) * 256 + col;
    hold[r] = fdt ? bf2f(((const unsigned short*)hinit)[idx]) : ((const float*)hinit)[idx];
  }

  // stage x_0 and h_0 (bf16): thread -> row tid>>6, 4 elems at (tid&63)*4
  {
    const int row = tid >> 6, c4 = (tid & 63) * 4;
    const int nd = nodes[d0 + row];
    if (fdt){
      *(uint64_t*)&xstg[0][row * LSTR + c4] =
          *(const uint64_t*)((const unsigned short*)emb + (size_t)nd * 256 + c4);
      *(uint64_t*)&hstg[0][row * LSTR + c4] =
          *(const uint64_t*)((const unsigned short*)hinit + (size_t)(d0 + row) * 256 + c4);
    } else {
      const float* sx = (const float*)emb   + (size_t)nd * 256 + c4;
      const float* sh = (const float*)hinit + (size_t)(d0 + row) * 256 + c4;
      #pragma unroll
      for (int j = 0; j < 4; ++j){
        xstg[0][row * LSTR + c4 + j] = f2bf(sx[j]);
        hstg[0][row * LSTR + c4 + j] = f2bf(sh[j]);
      }
    }
  }

  // edges for t=0 (rows quad*4+r)
  int ef[4];
  {
    const int base = d0 + quad * 4;
    if (efmt == 0){      for (int r = 0; r < 4; ++r) ef[r] = edges[base + r] != 0; }
    else if (efmt == 1){ for (int r = 0; r < 4; ++r) ef[r] = ((const int*)edges)[base + r] != 0; }
    else if (efmt == 3){ for (int r = 0; r < 4; ++r) ef[r] = ((const unsigned short*)edges)[base + r] != 0; }
    else {               for (int r = 0; r < 4; ++r) ef[r] = ((const float*)edges)[base + r] != 0.0f; }
  }
  __syncthreads();

  // ---------------- main recurrence: fully block-local ----------------
  for (int t = 0; t < TT; ++t){
    // stage x_{t+1} early (gmem latency hides under the GEMM below)
    if (t < TT - 1){
      const int row = tid >> 6, c4 = (tid & 63) * 4;
      const int nd = nodes[(t + 1) * DDIM + d0 + row];
      if (fdt){
        *(uint64_t*)&xstg[(t + 1) & 1][row * LSTR + c4] =
            *(const uint64_t*)((const unsigned short*)emb + (size_t)nd * 256 + c4);
      } else {
        const float* sx = (const float*)emb + (size_t)nd * 256 + c4;
        #pragma unroll
        for (int j = 0; j < 4; ++j) xstg[(t + 1) & 1][row * LSTR + c4 + j] = f2bf(sx[j]);
      }
    }

    // merged K=512 GEMM: kc 0..7 = x @ Wih.T, kc 8..15 = h @ Whh.T
    // acc: r,z merged chains; n split into x-side (aNI) and h-side (aNH)
    const unsigned short* xc = xstg[t & 1];
    const unsigned short* hc = hstg[t & 1];
    float4v aR[2], aZ[2], aNI[2], aNH[2];
    #pragma unroll
    for (int g = 0; g < 2; ++g){
      aR[g]  = splat4(bRZ[g][0]);
      aZ[g]  = splat4(bRZ[g][1]);
      aNI[g] = splat4(bNI[g]);
      aNH[g] = splat4(bNH[g]);
    }
    #pragma unroll
    for (int kc = 0; kc < 16; ++kc){
      const int k7 = kc & 7;
      const unsigned short* ab = (kc < 8) ? xc : hc;
      short8 a = *(const short8*)&ab[l16 * LSTR + k7 * 32 + quad * 8];
      #pragma unroll
      for (int g = 0; g < 2; ++g){
        short8 b0, b1, b2;
        if (fdt){
          const unsigned short* wp =
              (const unsigned short*)((kc < 8) ? WihP[g] : WhhP[g]) + coff + (size_t)k7 * 32;
          b0 = *(const short8*)(wp);
          b1 = *(const short8*)(wp + 65536);
          b2 = *(const short8*)(wp + 131072);
        } else {
          const float* wp = (const float*)((kc < 8) ? WihP[g] : WhhP[g]) + coff + (size_t)k7 * 32;
          #pragma unroll
          for (int j = 0; j < 8; ++j){
            b0[j] = (short)f2bf(wp[j]);
            b1[j] = (short)f2bf(wp[65536 + j]);
            b2[j] = (short)f2bf(wp[131072 + j]);
          }
        }
        aR[g] = __builtin_amdgcn_mfma_f32_16x16x32_bf16(a, b0, aR[g], 0, 0, 0);
        aZ[g] = __builtin_amdgcn_mfma_f32_16x16x32_bf16(a, b1, aZ[g], 0, 0, 0);
        if (kc < 8) aNI[g] = __builtin_amdgcn_mfma_f32_16x16x32_bf16(a, b2, aNI[g], 0, 0, 0);
        else        aNH[g] = __builtin_amdgcn_mfma_f32_16x16x32_bf16(a, b2, aNH[g], 0, 0, 0);
      }
    }

    // prefetch edges for t+1
    int efn[4];
    if (t < TT - 1){
      const int eb = (t + 1) * DDIM + d0 + quad * 4;
      if (efmt == 0){      for (int r = 0; r < 4; ++r) efn[r] = edges[eb + r] != 0; }
      else if (efmt == 1){ for (int r = 0; r < 4; ++r) efn[r] = ((const int*)edges)[eb + r] != 0; }
      else if (efmt == 3){ for (int r = 0; r < 4; ++r) efn[r] = ((const unsigned short*)edges)[eb + r] != 0; }
      else {               for (int r = 0; r < 4; ++r) efn[r] = ((const float*)edges)[eb + r] != 0.0f; }
    } else {
      #pragma unroll
      for (int r = 0; r < 4; ++r) efn[r] = 0;
    }

    // gates: both GRUs per thread, select locally by edge (edge -> child = gru 0)
    float cand[4];
    #pragma unroll
    for (int r = 0; r < 4; ++r){
      float c01[2];
      #pragma unroll
      for (int g = 0; g < 2; ++g){
        const float pr = aR[g][r];
        const float pz = aZ[g][r];
        const float R  = 1.0f / (1.0f + exp2f(-1.4426950408889634f * pr));
        const float Z  = 1.0f / (1.0f + exp2f(-1.4426950408889634f * pz));
        float ag = aNI[g][r] + R * aNH[g][r];
        ag = fminf(30.0f, fmaxf(-30.0f, ag));
        const float ex = exp2f(-2.8853900817779268f * ag);
        const float N  = (1.0f - ex) / (1.0f + ex);
        c01[g] = N + Z * (hold[r] - N);
      }
      cand[r] = ef[r] ? c01[0] : c01[1];
      hold[r] = cand[r];
    }

    // writes: h_{t+1} bf16 -> hstg[(t+1)&1]; out[t] (+ dup slab 256 at t=255)
    #pragma unroll
    for (int r = 0; r < 4; ++r){
      const int row = quad * 4 + r;
      const uint32_t bb = (uint32_t)f2bf(cand[r]);
      const uint32_t ob = (uint32_t)__shfl_xor((int)bb, 1, 64);
      const uint32_t pk = bb | (ob << 16);
      if (!(lane & 1)){   // even col: pack (col, col+1)
        if (t < TT - 1)
          *(uint32_t*)&hstg[(t + 1) & 1][row * LSTR + col] = pk;
        if (fdt){
          unsigned short* o16 = (unsigned short*)out;
          *(uint32_t*)(o16 + (size_t)t * 131072 + (size_t)(d0 + row) * 256 + col) = pk;
          if (t == TT - 1)
            *(uint32_t*)(o16 + (size_t)256 * 131072 + (size_t)(d0 + row) * 256 + col) = pk;
        }
      }
      if (!fdt){
        float* o32 = (float*)out;
        o32[(size_t)t * 131072 + (size_t)(d0 + row) * 256 + col] = cand[r];
        if (t == TT - 1)
          o32[(size_t)256 * 131072 + (size_t)(d0 + row) * 256 + col] = cand[r];
      }
    }

    #pragma unroll
    for (int r = 0; r < 4; ++r) ef[r] = efn[r];
    __syncthreads();   // xstg/hstg buffer (t+1)&1 ready; reads of t&1 done
  }
}

extern "C" void kernel_launch(void* const* d_in, const int* in_sizes, int n_in,
                              void* d_out, int out_size, void* d_ws, size_t ws_size,
                              hipStream_t stream)
{
  const int*           nodes = (const int*)d_in[0];
  const unsigned char* edges = (const unsigned char*)d_in[1];
  const unsigned char* hinit = (const unsigned char*)d_in[2];
  const unsigned char* emb   = (const unsigned char*)d_in[3];
  const unsigned char* cWih  = (const unsigned char*)d_in[4];
  const unsigned char* cWhh  = (const unsigned char*)d_in[5];
  const unsigned char* cbih  = (const unsigned char*)d_in[6];
  const unsigned char* cbhh  = (const unsigned char*)d_in[7];
  const unsigned char* sWih  = (const unsigned char*)d_in[8];
  const unsigned char* sWhh  = (const unsigned char*)d_in[9];
  const unsigned char* sbih  = (const unsigned char*)d_in[10];
  const unsigned char* sbhh  = (const unsigned char*)d_in[11];
  (void)in_sizes; (void)n_in; (void)out_size; (void)d_ws; (void)ws_size;

  // 32 independent blocks (16 rows each), 1024 threads: no workspace, no
  // cross-block sync, no dispatch/XCD assumptions.
  treernn_main<<<dim3(32), dim3(1024), 0, stream>>>(
      nodes, edges, hinit, emb, cWih, cWhh, cbih, cbhh, sWih, sWhh, sbih, sbhh,
      (unsigned char*)d_out);
}

// Round 5
// 1258.157 us; speedup vs baseline: 22.4700x; 22.4700x over previous
//
#include <hip/hip_runtime.h>
#include <stdint.h>

// R9: TreeRNN T=256, D=512, H=E=256, V=8192.
// R4's proven LLC exchange protocol, verbatim, on a smaller sync domain:
//   group = 16 rows (was 32), block = 16 rows x 32 cols x both GRUs.
//   grid 256 = 32 groups x 8 col-slices; block = 4 waves (gru x col-half),
//   per-wave weights in VGPRs identical to R4 (192 VGPR B-fragments).
// Per group: 8 blocks, 32 per-wave flags (was 64), 8 KB gather (was 16 KB).
// Publish: agent-scope exchange stores -> vmcnt(0) drain -> relaxed flag;
// poll 32 flags with ballot + s_sleep; gather agent-relaxed u64s. All bounded.
// Out stores: own (row,col) slice, deferred one step (ack during next poll);
// no slice-0 special case, no epilogue gather (final stores from registers).

#define TT   256
#define DDIM 512
#define LSTR 264   // LDS row stride in bf16 elems (256 + 8 pad)

typedef float    float4v __attribute__((ext_vector_type(4)));
typedef short    short8  __attribute__((ext_vector_type(8)));
typedef uint32_t uint4v  __attribute__((ext_vector_type(4)));

__device__ __forceinline__ unsigned short f2bf(float f){
  uint32_t u = __float_as_uint(f);
  u += 0x7fffu + ((u >> 16) & 1u);          // RNE, finite inputs
  return (unsigned short)(u >> 16);
}
__device__ __forceinline__ float bf2f(unsigned short h){
  return __uint_as_float(((uint32_t)h) << 16);
}
__device__ __forceinline__ float4v splat4(float v){ return (float4v){v, v, v, v}; }

__global__ __launch_bounds__(256, 1)
void treernn_main(const int* __restrict__ nodes,
                  const unsigned char* __restrict__ edges,
                  const unsigned char* __restrict__ hinit,
                  const unsigned char* __restrict__ emb,
                  const unsigned char* __restrict__ cWih, const unsigned char* __restrict__ cWhh,
                  const unsigned char* __restrict__ cbih, const unsigned char* __restrict__ cbhh,
                  const unsigned char* __restrict__ sWih, const unsigned char* __restrict__ sWhh,
                  const unsigned char* __restrict__ sbih, const unsigned char* __restrict__ sbhh,
                  unsigned char* __restrict__ out,
                  unsigned char* __restrict__ ws)
{
  __shared__ __align__(16) unsigned short xs[2][16 * LSTR];  // x_t bf16, dbuf
  __shared__ __align__(16) unsigned short hstg[16 * LSTR];   // h_t bf16 (gathered)
  __shared__ float hold[16 * 33];                            // fp32 carry, cols cs*32..+32
  __shared__ int det[8];

  const int tid  = threadIdx.x;
  const int lane = tid & 63;
  const int wv   = tid >> 6;
  const int gru  = wv >> 1;         // 0 = child GRU, 1 = sibling GRU
  const int ch   = wv & 1;          // 16-col half of the 32-col slice
  const int quad = lane >> 4;
  const int l16  = lane & 15;
  const int bid  = blockIdx.x;

  const int G    = bid >> 3;        // group: rows [G*16, +16), 32 groups
  const int cs   = bid & 7;         // col-slice: cols [cs*32, +32)
  const int d0   = G * 16;
  const int colw = ch * 16 + l16;   // col within slice
  const int col  = cs * 32 + colw;  // global h-col

  // ---------------- runtime dtype detection (R4 verbatim) ----------------
  if (tid < 8) det[tid] = 0;
  __syncthreads();
  {
    const unsigned short* hu = (const unsigned short*)hinit;
    int ce = 0;
    for (int i = tid; i < 4096; i += 256){
      const int e = (hu[i] >> 7) & 0xFF;
      ce += (e >= 100 && e <= 130) ? 1 : 0;
    }
    atomicAdd(&det[0], ce);
    const uint32_t* ewp = (const uint32_t*)edges;
    int b01 = 0, w01 = 0, wf = 0, hb = 0;
    for (int i = tid; i < 512; i += 256){
      const uint32_t w = ewp[i];
      w01 += (w <= 1u) ? 1 : 0;
      wf  += (w == 0u || w == 0x3F800000u) ? 1 : 0;
      const uint32_t h0 = w & 0xFFFFu, h1 = w >> 16;
      hb  += ((h0 == 0u || h0 == 0x3F80u) ? 1 : 0) + ((h1 == 0u || h1 == 0x3F80u) ? 1 : 0);
      b01 += (((w      ) & 0xFFu) <= 1u ? 1 : 0) + (((w >> 8 ) & 0xFFu) <= 1u ? 1 : 0)
           + (((w >> 16) & 0xFFu) <= 1u ? 1 : 0) + (((w >> 24)        ) <= 1u ? 1 : 0);
    }
    atomicAdd(&det[1], b01); atomicAdd(&det[2], w01);
    atomicAdd(&det[3], wf);  atomicAdd(&det[4], hb);
  }
  __syncthreads();
  const int fdt = (det[0] >= 3480) ? 1 : 0;   // 1 = floats are bf16
  int efmt;                                    // 0=u8, 1=i32, 2=f32, 3=bf16
  if      (det[2] == 512)  efmt = 1;
  else if (det[1] == 2048) efmt = 0;
  else if (det[4] == 1024) efmt = 3;
  else if (det[3] == 512)  efmt = 2;
  else                     efmt = 0;

  uint32_t*       flg = (uint32_t*)ws;                 // [32 groups][32 wave-flags]
  unsigned short* xbp = (unsigned short*)(ws + 16384); // [2][512][256] bf16 exchange

  const unsigned char* Wihp = gru ? sWih : cWih;
  const unsigned char* Whhp = gru ? sWhh : cWhh;
  const unsigned char* bihp = gru ? sbih : cbih;
  const unsigned char* bhhp = gru ? sbhh : cbhh;

  float bI[3], bH[3];
  #pragma unroll
  for (int ga = 0; ga < 3; ++ga){
    if (fdt){
      bI[ga] = bf2f(((const unsigned short*)bihp)[ga * 256 + col]);
      bH[ga] = bf2f(((const unsigned short*)bhhp)[ga * 256 + col]);
    } else {
      bI[ga] = ((const float*)bihp)[ga * 256 + col];
      bH[ga] = ((const float*)bhhp)[ga * 256 + col];
    }
  }

  // Weight slices -> bf16 MFMA B-fragments (R4 layout: B[k=quad*8+j][n=l16])
  short8 wI[3][8], wH[3][8];
  for (int ga = 0; ga < 3; ++ga){
    const int rw = ga * 256 + col;
    for (int kc = 0; kc < 8; ++kc){
      const int ke = kc * 32 + quad * 8;
      if (fdt){
        wI[ga][kc] = *(const short8*)((const unsigned short*)Wihp + (size_t)rw * 256 + ke);
        wH[ga][kc] = *(const short8*)((const unsigned short*)Whhp + (size_t)rw * 256 + ke);
      } else {
        const float* pI = (const float*)Wihp + (size_t)rw * 256 + ke;
        const float* pH = (const float*)Whhp + (size_t)rw * 256 + ke;
        short8 va, vb;
        #pragma unroll
        for (int j = 0; j < 8; ++j){ va[j] = (short)f2bf(pI[j]); vb[j] = (short)f2bf(pH[j]); }
        wI[ga][kc] = va; wH[ga][kc] = vb;
      }
    }
  }

  // ---------------- stage x_0, h_0 (bf16), hold (fp32), edges_0 ----------------
  {
    const int row = tid >> 4, cb = (tid & 15) * 16;   // 16 elems = 32 B per thread
    const int nd = nodes[d0 + row];
    unsigned short* xdst = &xs[0][row * LSTR + cb];
    unsigned short* hdst = &hstg[row * LSTR + cb];
    if (fdt){
      const unsigned short* sx = (const unsigned short*)emb   + (size_t)nd * 256 + cb;
      const unsigned short* sh = (const unsigned short*)hinit + (size_t)(d0 + row) * 256 + cb;
      *(uint4v*)xdst       = *(const uint4v*)sx;
      *(uint4v*)(xdst + 8) = *(const uint4v*)(sx + 8);
      *(uint4v*)hdst       = *(const uint4v*)sh;
      *(uint4v*)(hdst + 8) = *(const uint4v*)(sh + 8);
    } else {
      const float* sx = (const float*)emb   + (size_t)nd * 256 + cb;
      const float* sh = (const float*)hinit + (size_t)(d0 + row) * 256 + cb;
      short8 v0, v1, w0, w1;
      #pragma unroll
      for (int j = 0; j < 8; ++j){
        v0[j] = (short)f2bf(sx[j]); v1[j] = (short)f2bf(sx[8 + j]);
        w0[j] = (short)f2bf(sh[j]); w1[j] = (short)f2bf(sh[8 + j]);
      }
      *(short8*)xdst = v0; *(short8*)(xdst + 8) = v1;
      *(short8*)hdst = w0; *(short8*)(hdst + 8) = w1;
    }
    if (gru == 0){   // 2 waves cover rows(quad) x colw: fp32 carry init
      #pragma unroll
      for (int r = 0; r < 4; ++r){
        const size_t si = (size_t)(d0 + quad * 4 + r) * 256 + col;
        hold[(quad * 4 + r) * 33 + colw] =
            fdt ? bf2f(((const unsigned short*)hinit)[si]) : ((const float*)hinit)[si];
      }
    }
  }
  int ef[4];
  {
    const int base = d0 + quad * 4;
    if (efmt == 0){      for (int r = 0; r < 4; ++r) ef[r] = edges[base + r] != 0; }
    else if (efmt == 1){ for (int r = 0; r < 4; ++r) ef[r] = ((const int*)edges)[base + r] != 0; }
    else if (efmt == 3){ for (int r = 0; r < 4; ++r) ef[r] = ((const unsigned short*)edges)[base + r] != 0; }
    else {               for (int r = 0; r < 4; ++r) ef[r] = ((const float*)edges)[base + r] != 0.0f; }
  }
  __syncthreads();

  const int grow = tid >> 4;    // gather row (16 rows x 16 threads)
  const int gsub = tid & 15;    // 32-B chunk within row
  uint32_t* flgG = flg + G * 32;

  uint32_t sPk[4] = {0, 0, 0, 0};
  float    sCd[4] = {0, 0, 0, 0};
  int      sMn[4] = {0, 0, 0, 0};

  // ---------------- main recurrence ----------------
  for (int t = 0; t < TT; ++t){
    // ---- deferred out[t-1] from saved regs (acks during ih-GEMM + poll) ----
    if (t > 0){
      #pragma unroll
      for (int r = 0; r < 4; ++r){
        const int row = quad * 4 + r;
        if (fdt){
          if (sMn[r] && !(lane & 1)){
            unsigned short* o16 = (unsigned short*)out;
            *(uint32_t*)(o16 + (size_t)(t - 1) * 131072 + (size_t)(d0 + row) * 256 + col) = sPk[r];
          }
        } else {
          if (sMn[r]){
            float* o32 = (float*)out;
            o32[(size_t)(t - 1) * 131072 + (size_t)(d0 + row) * 256 + col] = sCd[r];
          }
        }
      }
    }

    // ---- ih-GEMM on staged x_t (peer-independent: runs before the poll) ----
    float4v aI[3];
    #pragma unroll
    for (int ga = 0; ga < 3; ++ga) aI[ga] = splat4(bI[ga]);
    {
      const unsigned short* xc = xs[t & 1];
      #pragma unroll
      for (int kc = 0; kc < 8; ++kc){
        short8 a = *(const short8*)&xc[l16 * LSTR + kc * 32 + quad * 8];
        #pragma unroll
        for (int ga = 0; ga < 3; ++ga)
          aI[ga] = __builtin_amdgcn_mfma_f32_16x16x32_bf16(a, wI[ga][kc], aI[ga], 0, 0, 0);
      }
    }

    // ---- fp32 state carry read (writes happen after B1) ----
    float hold4[4];
    #pragma unroll
    for (int r = 0; r < 4; ++r) hold4[r] = hold[(quad * 4 + r) * 33 + colw];

    // ---- poll 32 per-wave flags (ballot, relaxed), then gather 8 KB ----
    if (t > 0){
      const uint32_t target = (uint32_t)t;
      const uint32_t* fp = flgG + (lane & 31);
      uint32_t fv = __hip_atomic_load(fp, __ATOMIC_RELAXED, __HIP_MEMORY_SCOPE_AGENT);
      int guard = 0;
      while (__ballot(fv < target) != 0ull){
        __builtin_amdgcn_s_sleep(1);
        fv = __hip_atomic_load(fp, __ATOMIC_RELAXED, __HIP_MEMORY_SCOPE_AGENT);
        if (++guard > (1 << 17)) break;   // bounded: broken sync -> garbage, not hang
      }
      __atomic_signal_fence(__ATOMIC_SEQ_CST);
      const uint64_t* src = (const uint64_t*)(xbp + ((size_t)(t & 1) * 512 + d0 + grow) * 256
                                                  + gsub * 16);
      uint64_t a0 = __hip_atomic_load(src + 0, __ATOMIC_RELAXED, __HIP_MEMORY_SCOPE_AGENT);
      uint64_t a1 = __hip_atomic_load(src + 1, __ATOMIC_RELAXED, __HIP_MEMORY_SCOPE_AGENT);
      uint64_t a2 = __hip_atomic_load(src + 2, __ATOMIC_RELAXED, __HIP_MEMORY_SCOPE_AGENT);
      uint64_t a3 = __hip_atomic_load(src + 3, __ATOMIC_RELAXED, __HIP_MEMORY_SCOPE_AGENT);
      unsigned short* dst = &hstg[grow * LSTR + gsub * 16];
      *(uint64_t*)(dst + 0)  = a0;
      *(uint64_t*)(dst + 4)  = a1;
      *(uint64_t*)(dst + 8)  = a2;
      *(uint64_t*)(dst + 12) = a3;
    }
    __syncthreads();   // B1: hstg ready; hold reads done before hold writes

    // ---- hh-GEMM ----
    float4v aH[3];
    #pragma unroll
    for (int ga = 0; ga < 3; ++ga) aH[ga] = splat4(bH[ga]);
    #pragma unroll
    for (int kc = 0; kc < 8; ++kc){
      short8 a = *(const short8*)&hstg[l16 * LSTR + kc * 32 + quad * 8];
      #pragma unroll
      for (int ga = 0; ga < 3; ++ga)
        aH[ga] = __builtin_amdgcn_mfma_f32_16x16x32_bf16(a, wH[ga][kc], aH[ga], 0, 0, 0);
    }

    // ---- gates ----
    float cand[4]; int mine[4];
    #pragma unroll
    for (int r = 0; r < 4; ++r){
      const float pr = aI[0][r] + aH[0][r];
      const float pz = aI[1][r] + aH[1][r];
      const float R  = 1.0f / (1.0f + exp2f(-1.4426950408889634f * pr));
      const float Z  = 1.0f / (1.0f + exp2f(-1.4426950408889634f * pz));
      float ag = aI[2][r] + R * aH[2][r];
      ag = fminf(30.0f, fmaxf(-30.0f, ag));
      const float ex = exp2f(-2.8853900817779268f * ag);
      const float N  = (1.0f - ex) / (1.0f + ex);
      cand[r] = N + Z * (hold4[r] - N);
      mine[r] = ((ef[r] != 0) == (gru == 0)) ? 1 : 0;   // edge -> child GRU
    }

    // ---- local fp32 carry + exchange stores + save out regs ----
    const int buf = (t + 1) & 1;
    #pragma unroll
    for (int r = 0; r < 4; ++r){
      const int row = quad * 4 + r;
      if (mine[r]) hold[row * 33 + colw] = cand[r];
      const uint32_t bb = (uint32_t)f2bf(cand[r]);
      const uint32_t ob = (uint32_t)__shfl_xor((int)bb, 1, 64);
      const uint32_t pk = bb | (ob << 16);
      sPk[r] = pk; sCd[r] = cand[r]; sMn[r] = mine[r];
      if (t < TT - 1 && mine[r] && !(lane & 1)){
        uint32_t* xp = (uint32_t*)&xbp[((size_t)buf * 512 + d0 + row) * 256 + col];
        __hip_atomic_store(xp, pk, __ATOMIC_RELAXED, __HIP_MEMORY_SCOPE_AGENT);
      }
    }

    if (t < TT - 1){
      // ---- publish: drain this wave's stores, then RELAXED per-wave flag ----
      __atomic_signal_fence(__ATOMIC_SEQ_CST);
      __builtin_amdgcn_s_waitcnt(0x0F70);   // vmcnt(0)
      __atomic_signal_fence(__ATOMIC_SEQ_CST);
      if (lane == 0)
        __hip_atomic_store(flgG + cs * 4 + wv, (uint32_t)(t + 1),
                           __ATOMIC_RELAXED, __HIP_MEMORY_SCOPE_AGENT);

      // ---- prefetch x_{t+1} + edges_{t+1} (after publish: off critical chain) ----
      {
        const int row = tid >> 4, cb = (tid & 15) * 16;
        const int nd = nodes[(t + 1) * DDIM + d0 + row];
        unsigned short* dst = &xs[buf][row * LSTR + cb];
        if (fdt){
          const unsigned short* s = (const unsigned short*)emb + (size_t)nd * 256 + cb;
          uint4v r0 = *(const uint4v*)s;
          uint4v r1 = *(const uint4v*)(s + 8);
          *(uint4v*)dst       = r0;
          *(uint4v*)(dst + 8) = r1;
        } else {
          const float* s = (const float*)emb + (size_t)nd * 256 + cb;
          short8 v0, v1;
          #pragma unroll
          for (int j = 0; j < 8; ++j){ v0[j] = (short)f2bf(s[j]); v1[j] = (short)f2bf(s[8 + j]); }
          *(short8*)dst       = v0;
          *(short8*)(dst + 8) = v1;
        }
        const int eb = (t + 1) * DDIM + d0 + quad * 4;
        if (efmt == 0){      for (int r2 = 0; r2 < 4; ++r2) ef[r2] = edges[eb + r2] != 0; }
        else if (efmt == 1){ for (int r2 = 0; r2 < 4; ++r2) ef[r2] = ((const int*)edges)[eb + r2] != 0; }
        else if (efmt == 3){ for (int r2 = 0; r2 < 4; ++r2) ef[r2] = ((const unsigned short*)edges)[eb + r2] != 0; }
        else {               for (int r2 = 0; r2 < 4; ++r2) ef[r2] = ((const float*)edges)[eb + r2] != 0.0f; }
      }
    }

    __syncthreads();   // B2: xs[t+1]/hold ready; hstg reads done before next gather
  }

  // ---- epilogue: out[255] + duplicated h_final slab from saved regs ----
  #pragma unroll
  for (int r = 0; r < 4; ++r){
    const int row = quad * 4 + r;
    if (fdt){
      if (sMn[r] && !(lane & 1)){
        unsigned short* o16 = (unsigned short*)out;
        *(uint32_t*)(o16 + (size_t)255 * 131072 + (size_t)(d0 + row) * 256 + col) = sPk[r];
        *(uint32_t*)(o16 + (size_t)256 * 131072 + (size_t)(d0 + row) * 256 + col) = sPk[r];
      }
    } else {
      if (sMn[r]){
        float* o32 = (float*)out;
        o32[(size_t)255 * 131072 + (size_t)(d0 + row) * 256 + col] = sCd[r];
        o32[(size_t)256 * 131072 + (size_t)(d0 + row) * 256 + col] = sCd[r];
      }
    }
  }
}

extern "C" void kernel_launch(void* const* d_in, const int* in_sizes, int n_in,
                              void* d_out, int out_size, void* d_ws, size_t ws_size,
                              hipStream_t stream)
{
  const int*           nodes = (const int*)d_in[0];
  const unsigned char* edges = (const unsigned char*)d_in[1];
  const unsigned char* hinit = (const unsigned char*)d_in[2];
  const unsigned char* emb   = (const unsigned char*)d_in[3];
  const unsigned char* cWih  = (const unsigned char*)d_in[4];
  const unsigned char* cWhh  = (const unsigned char*)d_in[5];
  const unsigned char* cbih  = (const unsigned char*)d_in[6];
  const unsigned char* cbhh  = (const unsigned char*)d_in[7];
  const unsigned char* sWih  = (const unsigned char*)d_in[8];
  const unsigned char* sWhh  = (const unsigned char*)d_in[9];
  const unsigned char* sbih  = (const unsigned char*)d_in[10];
  const unsigned char* sbhh  = (const unsigned char*)d_in[11];
  (void)in_sizes; (void)n_in; (void)out_size; (void)ws_size;

  // zero flag region (ws re-poisoned before every launch)
  hipMemsetAsync(d_ws, 0, 8192, stream);

  treernn_main<<<dim3(256), dim3(256), 0, stream>>>(
      nodes, edges, hinit, emb, cWih, cWhh, cbih, cbhh, sWih, sWhh, sbih, sbhh,
      (unsigned char*)d_out, (unsigned char*)d_ws);
}